// Round 2
// baseline (458.185 us; speedup 1.0000x reference)
//
#include <hip/hip_runtime.h>
#include <stdint.h>

#define NROWS 262144
#define DDIM 128
#define NCLS 512
constexpr float INV_BETA = 10.0f;

typedef __bf16 v8bf __attribute__((ext_vector_type(8)));
typedef float v4f __attribute__((ext_vector_type(4)));

__device__ inline unsigned short f2bf(float f) {
    uint32_t u = __builtin_bit_cast(uint32_t, f);
    u += 0x7FFFu + ((u >> 16) & 1u);
    return (unsigned short)(u >> 16);
}
__device__ inline float bf2f(unsigned short h) {
    uint32_t u = ((uint32_t)h) << 16;
    return __builtin_bit_cast(float, u);
}
__device__ inline float bflo(uint32_t u) { return __builtin_bit_cast(float, u << 16); }
__device__ inline float bfhi(uint32_t u) { return __builtin_bit_cast(float, u & 0xFFFF0000u); }

// K1: L2-normalize rows of inputs, write bf16; count classes.
__global__ __launch_bounds__(256) void k1_normalize(
    const float* __restrict__ in, const int* __restrict__ tgt,
    unsigned short* __restrict__ xb, int* __restrict__ counts) {
    int t = threadIdx.x;
    int l = t & 63;
    int w = t >> 6;
    int half = l >> 5;
    int lane32 = l & 31;
    for (int row = blockIdx.x * 8 + w * 2 + half; row < NROWS; row += gridDim.x * 8) {
        const float4 v = *reinterpret_cast<const float4*>(in + (size_t)row * DDIM + lane32 * 4);
        float ss = v.x * v.x + v.y * v.y + v.z * v.z + v.w * v.w;
        for (int off = 1; off < 32; off <<= 1) ss += __shfl_xor(ss, off);
        float inv = 1.0f / fmaxf(sqrtf(ss), 1e-12f);
        ushort4 o;
        o.x = f2bf(v.x * inv); o.y = f2bf(v.y * inv);
        o.z = f2bf(v.z * inv); o.w = f2bf(v.w * inv);
        *reinterpret_cast<ushort4*>(xb + (size_t)row * DDIM + lane32 * 4) = o;
        if (lane32 == 0) atomicAdd(counts + tgt[row], 1);
    }
}

// K2 v2: per-class sums. Tile = 512 classes x 16 dims f32 (32 KB -> 5 blocks/CU).
// Grid = 8 dim-chunks x nslice row-slices. uint4 loads (8 dims), unroll-4 ILP.
__global__ __launch_bounds__(256) void k2_csum(
    const unsigned short* __restrict__ xb, const int* __restrict__ tgt,
    float* __restrict__ partial, int nslice) {
    extern __shared__ float tile[];  // 512*16 floats = 32 KB
    int t = threadIdx.x;
    int dc = blockIdx.x & 7;         // dim chunk (16 dims)
    int slice = blockIdx.x >> 3;     // row slice
    for (int i = t; i < NCLS * 16; i += 256) tile[i] = 0.0f;
    __syncthreads();
    int rows_per_slice = NROWS / nslice;
    int row_base = slice * rows_per_slice;
    int g = t & 1;       // 8-dim half of the 16-dim chunk
    int rsub = t >> 1;   // 0..127 rows per iter
    int iters = rows_per_slice / 128;
    for (int it = 0; it < iters; it += 4) {
        uint4 v[4]; int c[4];
#pragma unroll
        for (int j = 0; j < 4; ++j) {
            int row = row_base + (it + j) * 128 + rsub;
            v[j] = *reinterpret_cast<const uint4*>(xb + (size_t)row * DDIM + dc * 16 + g * 8);
            c[j] = tgt[row];
        }
#pragma unroll
        for (int j = 0; j < 4; ++j) {
            int sw = c[j] & 15;
            float* base = tile + c[j] * 16;
            int d0 = g * 8;
            atomicAdd(base + ((d0 + 0) ^ sw), bflo(v[j].x));
            atomicAdd(base + ((d0 + 1) ^ sw), bfhi(v[j].x));
            atomicAdd(base + ((d0 + 2) ^ sw), bflo(v[j].y));
            atomicAdd(base + ((d0 + 3) ^ sw), bfhi(v[j].y));
            atomicAdd(base + ((d0 + 4) ^ sw), bflo(v[j].z));
            atomicAdd(base + ((d0 + 5) ^ sw), bfhi(v[j].z));
            atomicAdd(base + ((d0 + 6) ^ sw), bflo(v[j].w));
            atomicAdd(base + ((d0 + 7) ^ sw), bfhi(v[j].w));
        }
    }
    __syncthreads();
    // write-out, unswizzled: partial[bid*8192 + c*16 + d]
    float* outp = partial + (size_t)blockIdx.x * (NCLS * 16);
    for (int i = t; i < NCLS * 16; i += 256) {
        int c = i >> 4, d = i & 15;
        outp[i] = tile[c * 16 + (d ^ (c & 15))];
    }
}

// K3: reduce partials over nslice slices, mean, L2-normalize, write bf16 centers.
__global__ __launch_bounds__(128) void k3_centers(
    const float* __restrict__ partial, const int* __restrict__ counts,
    unsigned short* __restrict__ cen, float* __restrict__ present, int nslice) {
    int c = blockIdx.x;
    int d = threadIdx.x;  // 0..127
    int dc = d >> 4, dim = d & 15;
    float s = 0.0f;
#pragma unroll 8
    for (int sl = 0; sl < nslice; ++sl)
        s += partial[(size_t)(sl * 8 + dc) * (NCLS * 16) + c * 16 + dim];
    int cnt = counts[c];
    float cm = s / fmaxf((float)cnt, 1.0f);
    float ss = cm * cm;
    for (int off = 1; off < 64; off <<= 1) ss += __shfl_xor(ss, off);
    __shared__ float red[2];
    if ((d & 63) == 0) red[d >> 6] = ss;
    __syncthreads();
    float tot = red[0] + red[1];
    float inv = 1.0f / fmaxf(sqrtf(tot), 1e-12f);
    cen[(size_t)c * DDIM + d] = f2bf(cm * inv);
    if (d == 0) present[c] = (cnt > 0) ? 1.0f : 0.0f;
}

// K4: per block: 64 samples x all 512 classes. Centers (128KB, swizzled) +
// x tile (16KB, swizzled) in LDS. 8 waves, wave w owns classes [w*64,w*64+64).
__global__ __launch_bounds__(512) void k4_loss(
    const unsigned short* __restrict__ xb, const unsigned short* __restrict__ cen,
    const float* __restrict__ present, const int* __restrict__ tgt,
    float* __restrict__ out) {
    extern __shared__ char lds[];
    char* cenL = lds;                          // 131072 B
    char* xL = lds + 131072;                   // 16384 B
    float* prsL = (float*)(lds + 147456);      // 512 f32
    int* tgtL = (int*)(lds + 149504);          // 64 int
    float* denL = (float*)(lds + 149760);      // 64 f32
    float* posL = (float*)(lds + 150016);      // 64 f32
    int t = threadIdx.x;
    int base = blockIdx.x * 64;

    for (int i = 0; i < 16; ++i) {
        int chunk = i * 512 + t;
        int row = chunk >> 4, c16 = chunk & 15;
        uint4 v = *reinterpret_cast<const uint4*>((const char*)cen + (size_t)chunk * 16);
        *reinterpret_cast<uint4*>(cenL + row * 256 + ((c16 * 16) ^ ((row & 7) << 4))) = v;
    }
    for (int i = 0; i < 2; ++i) {
        int chunk = i * 512 + t;
        int row = chunk >> 4, c16 = chunk & 15;
        uint4 v = *reinterpret_cast<const uint4*>((const char*)xb + (size_t)base * 256 + (size_t)chunk * 16);
        *reinterpret_cast<uint4*>(xL + row * 256 + ((c16 * 16) ^ ((row & 7) << 4))) = v;
    }
    prsL[t & 511] = present[t & 511];
    if (t < 64) { tgtL[t] = tgt[base + t]; denL[t] = 0.0f; posL[t] = 0.0f; }
    __syncthreads();

    int w = t >> 6, l = t & 63;
    int lm = l & 15, lk = l >> 4;
    v4f acc[4][4];
    v4f zero = {0.0f, 0.0f, 0.0f, 0.0f};
#pragma unroll
    for (int m = 0; m < 4; ++m)
#pragma unroll
        for (int n = 0; n < 4; ++n) acc[m][n] = zero;

#pragma unroll
    for (int kc = 0; kc < 4; ++kc) {
        int kb = kc * 64 + lk * 16;
        v8bf a[4], b[4];
#pragma unroll
        for (int m = 0; m < 4; ++m) {
            int row = w * 64 + m * 16 + lm;
            a[m] = *reinterpret_cast<const v8bf*>(cenL + row * 256 + (kb ^ ((row & 7) << 4)));
        }
#pragma unroll
        for (int n = 0; n < 4; ++n) {
            int row = n * 16 + lm;
            b[n] = *reinterpret_cast<const v8bf*>(xL + row * 256 + (kb ^ ((row & 7) << 4)));
        }
#pragma unroll
        for (int m = 0; m < 4; ++m)
#pragma unroll
            for (int n = 0; n < 4; ++n)
                acc[m][n] = __builtin_amdgcn_mfma_f32_16x16x32_bf16(a[m], b[n], acc[m][n], 0, 0, 0);
    }

#pragma unroll
    for (int n = 0; n < 4; ++n) {
        int s = n * 16 + lm;
        int ts = tgtL[s];
        float se = 0.0f, sp = 0.0f;
#pragma unroll
        for (int m = 0; m < 4; ++m) {
#pragma unroll
            for (int r = 0; r < 4; ++r) {
                int cls = w * 64 + m * 16 + lk * 4 + r;
                float logit = acc[m][n][r] * INV_BETA;
                se += prsL[cls] * __expf(logit);
                if (cls == ts) sp = logit;
            }
        }
        se += __shfl_xor(se, 16); se += __shfl_xor(se, 32);
        sp += __shfl_xor(sp, 16); sp += __shfl_xor(sp, 32);
        if (l < 16) { atomicAdd(&denL[s], se); atomicAdd(&posL[s], sp); }
    }
    __syncthreads();
    if (t < 64) {
        float li = __logf(denL[t]) - posL[t];
        for (int off = 1; off < 64; off <<= 1) li += __shfl_xor(li, off);
        if (t == 0) atomicAdd(out, li * (1.0f / NROWS));
    }
}

extern "C" void kernel_launch(void* const* d_in, const int* in_sizes, int n_in,
                              void* d_out, int out_size, void* d_ws, size_t ws_size,
                              hipStream_t stream) {
    const float* in = (const float*)d_in[0];
    const int* tgt = (const int*)d_in[1];
    float* out = (float*)d_out;
    char* ws = (char*)d_ws;
    unsigned short* xb = (unsigned short*)(ws);              // 67108864 B
    int* counts = (int*)(ws + 67108864);                     // 2048 B
    unsigned short* cen = (unsigned short*)(ws + 67110912);  // 131072 B
    float* present = (float*)(ws + 67241984);                // 2048 B
    float* partial = (float*)(ws + 67244032);                // up to 33.5 MB

    // nslice: 128 if ws holds 1024*8192*4B of partials, else 64 (84MB proven)
    size_t avail = ws_size > 67244032 ? ws_size - 67244032 : 0;
    int nslice = (avail >= (size_t)1024 * 8192 * 4) ? 128 : 64;

    (void)hipFuncSetAttribute((const void*)k4_loss,
                              hipFuncAttributeMaxDynamicSharedMemorySize, 150272);

    hipMemsetAsync(counts, 0, 2048, stream);
    hipMemsetAsync(out, 0, sizeof(float), stream);
    hipLaunchKernelGGL(k1_normalize, dim3(2048), dim3(256), 0, stream, in, tgt, xb, counts);
    hipLaunchKernelGGL(k2_csum, dim3(nslice * 8), dim3(256), 32768, stream, xb, tgt, partial, nslice);
    hipLaunchKernelGGL(k3_centers, dim3(512), dim3(128), 0, stream, partial, counts, cen, present, nslice);
    hipLaunchKernelGGL(k4_loss, dim3(4096), dim3(512), 150272, stream, xb, cen, present, tgt, out);
}

// Round 5
// 328.943 us; speedup vs baseline: 1.3929x; 1.3929x over previous
//
#include <hip/hip_runtime.h>
#include <stdint.h>

#define NROWS 262144
#define DDIM 128
#define NCLS 512
constexpr float INV_BETA = 10.0f;

typedef __bf16 v8bf __attribute__((ext_vector_type(8)));
typedef float v4f __attribute__((ext_vector_type(4)));

__device__ inline unsigned short f2bf(float f) {
    uint32_t u = __builtin_bit_cast(uint32_t, f);
    u += 0x7FFFu + ((u >> 16) & 1u);
    return (unsigned short)(u >> 16);
}
__device__ inline float bflo(uint32_t u) { return __builtin_bit_cast(float, u << 16); }
__device__ inline float bfhi(uint32_t u) { return __builtin_bit_cast(float, u & 0xFFFF0000u); }

// K1: L2-normalize rows -> bf16 xb; histogram counts via global atomics.
__global__ __launch_bounds__(256) void k1_normalize(
    const float* __restrict__ in, const int* __restrict__ tgt,
    unsigned short* __restrict__ xb, int* __restrict__ counts) {
    int t = threadIdx.x;
    int l = t & 63;
    int w = t >> 6;
    int half = l >> 5;
    int lane32 = l & 31;
    for (int row = blockIdx.x * 8 + w * 2 + half; row < NROWS; row += gridDim.x * 8) {
        const float4 v = *reinterpret_cast<const float4*>(in + (size_t)row * DDIM + lane32 * 4);
        float ss = v.x * v.x + v.y * v.y + v.z * v.z + v.w * v.w;
        for (int off = 1; off < 32; off <<= 1) ss += __shfl_xor(ss, off);
        float inv = 1.0f / fmaxf(sqrtf(ss), 1e-12f);
        ushort4 o;
        o.x = f2bf(v.x * inv); o.y = f2bf(v.y * inv);
        o.z = f2bf(v.z * inv); o.w = f2bf(v.w * inv);
        *reinterpret_cast<ushort4*>(xb + (size_t)row * DDIM + lane32 * 4) = o;
        if (lane32 == 0) atomicAdd(counts + tgt[row], 1);
    }
}

// Prefix sum over 512 counts (exclusive) + n_absent. One block of 512.
__global__ __launch_bounds__(512) void k_prefix(
    const int* __restrict__ counts, int* __restrict__ offs,
    int* __restrict__ cursor, float* __restrict__ nabsG) {
    __shared__ int sc[NCLS];
    __shared__ int za;
    int t = threadIdx.x;
    int c = counts[t];
    sc[t] = c;
    if (t == 0) za = 0;
    __syncthreads();
    for (int off = 1; off < NCLS; off <<= 1) {
        int v = (t >= off) ? sc[t - off] : 0;
        __syncthreads();
        sc[t] += v;
        __syncthreads();
    }
    int excl = sc[t] - c;
    offs[t] = excl;
    cursor[t] = excl;
    if (c == 0) atomicAdd(&za, 1);
    __syncthreads();
    if (t == 0) *nabsG = (float)za;
}

// Scatter row indices bucketed by class.
__global__ __launch_bounds__(256) void k_scatter(
    const int* __restrict__ tgt, int* __restrict__ cursor, int* __restrict__ ridx) {
    int i = blockIdx.x * 256 + threadIdx.x;
    int c = tgt[i];
    int pos = atomicAdd(&cursor[c], 1);
    ridx[pos] = i;
}

// Per-class mean + L2-normalize -> bf16 centers. 2 classes/block, 4 waves/class.
// Lane l accumulates dims 2l, 2l+1 in fp32 registers; gathered row loads are
// 256B coalesced per wave. No atomics.
__global__ __launch_bounds__(512) void k_centers(
    const unsigned short* __restrict__ xb, const int* __restrict__ ridx,
    const int* __restrict__ counts, const int* __restrict__ offs,
    unsigned short* __restrict__ cen) {
    __shared__ float2 sP[8][64];
    int t = threadIdx.x, w = t >> 6, l = t & 63;
    int cl = blockIdx.x * 2 + (w >> 2);
    int sub = w & 3;
    int cnt = counts[cl], start = offs[cl];
    const uint32_t* xb32 = (const uint32_t*)xb;
    float a0 = 0.0f, a1 = 0.0f;
    int per = (cnt + 3) >> 2;
    int lo = sub * per, hi = min(cnt, lo + per);
    int i = lo;
    for (; i + 8 <= hi; i += 8) {
        int id[8]; uint32_t v[8];
#pragma unroll
        for (int j = 0; j < 8; ++j) id[j] = ridx[start + i + j];
#pragma unroll
        for (int j = 0; j < 8; ++j) v[j] = xb32[(size_t)id[j] * 64 + l];
#pragma unroll
        for (int j = 0; j < 8; ++j) { a0 += bflo(v[j]); a1 += bfhi(v[j]); }
    }
    for (; i < hi; ++i) {
        uint32_t v = xb32[(size_t)ridx[start + i] * 64 + l];
        a0 += bflo(v); a1 += bfhi(v);
    }
    sP[w][l] = make_float2(a0, a1);
    __syncthreads();
    if ((w & 3) == 0) {
        float2 s0 = sP[w][l], s1 = sP[w + 1][l], s2 = sP[w + 2][l], s3 = sP[w + 3][l];
        float c0 = (s0.x + s1.x) + (s2.x + s3.x);
        float c1 = (s0.y + s1.y) + (s2.y + s3.y);
        float fc = fmaxf((float)cnt, 1.0f);
        c0 /= fc; c1 /= fc;
        float ss = c0 * c0 + c1 * c1;
        for (int off = 1; off < 64; off <<= 1) ss += __shfl_xor(ss, off);
        float inv = 1.0f / fmaxf(sqrtf(ss), 1e-12f);
        ushort2 o;
        o.x = f2bf(c0 * inv); o.y = f2bf(c1 * inv);
        *reinterpret_cast<ushort2*>(cen + (size_t)cl * DDIM + l * 2) = o;
    }
}

// K4 v2: 256 blocks x 8 waves. Wave w holds centers[w*64..w*64+64) as A-frags
// in registers (loaded once). 16 x-tiles of 64 samples, double-buffered 16KB
// LDS (XOR-swizzled). Absent classes contribute exp(0)=1 -> subtract nabs.
__global__ __launch_bounds__(512) void k4_loss(
    const unsigned short* __restrict__ xb, const unsigned short* __restrict__ cen,
    const int* __restrict__ tgt, const float* __restrict__ nabsG,
    float* __restrict__ out) {
    __shared__ char xL[2][16384];
    __shared__ float denP[8][64];
    __shared__ float posP[8][64];
    int t = threadIdx.x, w = t >> 6, l = t & 63;
    int lm = l & 15, lk = l >> 4;
    float nabs = *nabsG;

    // A fragments: row = class, dims [kc*32 + lk*8, +8)
    v8bf afr[4][4];
#pragma unroll
    for (int m = 0; m < 4; ++m)
#pragma unroll
        for (int kc = 0; kc < 4; ++kc) {
            int row = w * 64 + m * 16 + lm;
            afr[m][kc] = *reinterpret_cast<const v8bf*>(cen + (size_t)row * DDIM + kc * 32 + lk * 8);
        }

    int block0 = blockIdx.x * 1024;  // 16 tiles * 64 samples
    // staging: thread handles 16B chunks c0=2t, c0+1 of the 16KB tile
    int c0 = t * 2;
    int srow = c0 >> 4;
    int sw = (srow & 7) << 4;
    int dst0 = srow * 256 + (((c0 & 15) * 16) ^ sw);
    int dst1 = srow * 256 + ((((c0 & 15) + 1) * 16) ^ sw);
    const char* xbB = (const char*)xb;

    uint4 r0 = *(const uint4*)(xbB + (size_t)block0 * 256 + c0 * 16);
    uint4 r1 = *(const uint4*)(xbB + (size_t)block0 * 256 + c0 * 16 + 16);
    *(uint4*)(xL[0] + dst0) = r0;
    *(uint4*)(xL[0] + dst1) = r1;
    float lossAcc = 0.0f;
    __syncthreads();

    for (int tile = 0; tile < 16; ++tile) {
        int cur = tile & 1;
        int gbase = block0 + tile * 64;
        if (tile < 15) {
            const char* src = xbB + (size_t)(gbase + 64) * 256;
            r0 = *(const uint4*)(src + c0 * 16);
            r1 = *(const uint4*)(src + c0 * 16 + 16);
        }
        int ts[4];
#pragma unroll
        for (int n = 0; n < 4; ++n) ts[n] = tgt[gbase + n * 16 + lm];

        v4f acc[4][4];
        v4f zero = {0.0f, 0.0f, 0.0f, 0.0f};
#pragma unroll
        for (int m = 0; m < 4; ++m)
#pragma unroll
            for (int n = 0; n < 4; ++n) acc[m][n] = zero;

#pragma unroll
        for (int kc = 0; kc < 4; ++kc) {
            int kb = kc * 64 + lk * 16;
            v8bf b[4];
#pragma unroll
            for (int n = 0; n < 4; ++n) {
                int row = n * 16 + lm;
                b[n] = *reinterpret_cast<const v8bf*>(xL[cur] + row * 256 + (kb ^ ((row & 7) << 4)));
            }
#pragma unroll
            for (int m = 0; m < 4; ++m)
#pragma unroll
                for (int n = 0; n < 4; ++n)
                    acc[m][n] = __builtin_amdgcn_mfma_f32_16x16x32_bf16(afr[m][kc], b[n], acc[m][n], 0, 0, 0);
        }

        // epilogue: per sample col, sum exp over this wave's 64 classes
#pragma unroll
        for (int n = 0; n < 4; ++n) {
            float se = 0.0f, sp = 0.0f;
#pragma unroll
            for (int m = 0; m < 4; ++m) {
#pragma unroll
                for (int r = 0; r < 4; ++r) {
                    int cls = w * 64 + m * 16 + lk * 4 + r;
                    float logit = acc[m][n][r] * INV_BETA;
                    se += __expf(logit);
                    if (cls == ts[n]) sp = logit;
                }
            }
            se += __shfl_xor(se, 16); se += __shfl_xor(se, 32);
            sp += __shfl_xor(sp, 16); sp += __shfl_xor(sp, 32);
            if (l < 16) { denP[w][n * 16 + lm] = se; posP[w][n * 16 + lm] = sp; }
        }
        __syncthreads();
        if (tile < 15) {
            *(uint4*)(xL[1 - cur] + dst0) = r0;
            *(uint4*)(xL[1 - cur] + dst1) = r1;
        }
        if (w == 0) {
            float den = 0.0f, pos = 0.0f;
#pragma unroll
            for (int q = 0; q < 8; ++q) { den += denP[q][l]; pos += posP[q][l]; }
            lossAcc += __logf(den - nabs) - pos;
        }
        __syncthreads();
    }
    if (w == 0) {
        for (int off = 1; off < 64; off <<= 1) lossAcc += __shfl_xor(lossAcc, off);
        if (l == 0) atomicAdd(out, lossAcc * (1.0f / NROWS));
    }
}

extern "C" void kernel_launch(void* const* d_in, const int* in_sizes, int n_in,
                              void* d_out, int out_size, void* d_ws, size_t ws_size,
                              hipStream_t stream) {
    const float* in = (const float*)d_in[0];
    const int* tgt = (const int*)d_in[1];
    float* out = (float*)d_out;
    char* ws = (char*)d_ws;
    unsigned short* xb = (unsigned short*)(ws);              // 67108864 B
    int* counts = (int*)(ws + 67108864);                     // 2048 B
    int* offs = (int*)(ws + 67110912);                       // 2048 B
    int* cursor = (int*)(ws + 67112960);                     // 2048 B
    float* nabsG = (float*)(ws + 67115008);                  // 256 B (pad)
    unsigned short* cen = (unsigned short*)(ws + 67115264);  // 131072 B
    int* ridx = (int*)(ws + 67246336);                       // 1048576 B

    hipMemsetAsync(counts, 0, 2048, stream);
    hipMemsetAsync(out, 0, sizeof(float), stream);
    hipLaunchKernelGGL(k1_normalize, dim3(2048), dim3(256), 0, stream, in, tgt, xb, counts);
    hipLaunchKernelGGL(k_prefix, dim3(1), dim3(512), 0, stream, counts, offs, cursor, nabsG);
    hipLaunchKernelGGL(k_scatter, dim3(NROWS / 256), dim3(256), 0, stream, tgt, cursor, ridx);
    hipLaunchKernelGGL(k_centers, dim3(NCLS / 2), dim3(512), 0, stream, xb, ridx, counts, offs, cen);
    hipLaunchKernelGGL(k4_loss, dim3(256), dim3(512), 0, stream, xb, cen, tgt, nabsG, out);
}

// Round 6
// 205.692 us; speedup vs baseline: 2.2275x; 1.5992x over previous
//
#include <hip/hip_runtime.h>
#include <stdint.h>

#define NROWS 262144
#define DDIM 128
#define NCLS 512
constexpr float INV_BETA = 10.0f;

typedef __bf16 v8bf __attribute__((ext_vector_type(8)));
typedef float v4f __attribute__((ext_vector_type(4)));

__device__ inline unsigned short f2bf(float f) {
    uint32_t u = __builtin_bit_cast(uint32_t, f);
    u += 0x7FFFu + ((u >> 16) & 1u);
    return (unsigned short)(u >> 16);
}
__device__ inline float bflo(uint32_t u) { return __builtin_bit_cast(float, u << 16); }
__device__ inline float bfhi(uint32_t u) { return __builtin_bit_cast(float, u & 0xFFFF0000u); }

// K1 v2: pure streaming L2-normalize fp32 -> bf16. No atomics, no divergence.
// Half-wave (32 lanes) per row; 2 independent row-chunks in flight per iter.
__global__ __launch_bounds__(256) void k1_normalize(
    const float* __restrict__ in, unsigned short* __restrict__ xb) {
    int t = threadIdx.x;
    int w = t >> 6;
    int half = (t & 63) >> 5;
    int lane32 = t & 31;
    const int CH = NROWS / 2;  // 131072
    for (int row = blockIdx.x * 8 + w * 2 + half; row < CH; row += 2048 * 8) {
        int rowB = row + CH;
        const float4 v0 = *reinterpret_cast<const float4*>(in + (size_t)row * DDIM + lane32 * 4);
        const float4 v1 = *reinterpret_cast<const float4*>(in + (size_t)rowB * DDIM + lane32 * 4);
        float s0 = v0.x * v0.x + v0.y * v0.y + v0.z * v0.z + v0.w * v0.w;
        float s1 = v1.x * v1.x + v1.y * v1.y + v1.z * v1.z + v1.w * v1.w;
#pragma unroll
        for (int off = 1; off < 32; off <<= 1) {
            s0 += __shfl_xor(s0, off);
            s1 += __shfl_xor(s1, off);
        }
        float i0 = rsqrtf(fmaxf(s0, 1e-24f));
        float i1 = rsqrtf(fmaxf(s1, 1e-24f));
        ushort4 o0, o1;
        o0.x = f2bf(v0.x * i0); o0.y = f2bf(v0.y * i0);
        o0.z = f2bf(v0.z * i0); o0.w = f2bf(v0.w * i0);
        o1.x = f2bf(v1.x * i1); o1.y = f2bf(v1.y * i1);
        o1.z = f2bf(v1.z * i1); o1.w = f2bf(v1.w * i1);
        *reinterpret_cast<ushort4*>(xb + (size_t)row * DDIM + lane32 * 4) = o0;
        *reinterpret_cast<ushort4*>(xb + (size_t)rowB * DDIM + lane32 * 4) = o1;
    }
}

// Class histogram: LDS-privatized per block, one global merge per class/block.
__global__ __launch_bounds__(256) void k_hist(
    const int* __restrict__ tgt, int* __restrict__ counts) {
    __shared__ int h[NCLS];
    int t = threadIdx.x;
    for (int i = t; i < NCLS; i += 256) h[i] = 0;
    __syncthreads();
    int base = blockIdx.x * (NROWS / 128);
    for (int i = base + t; i < base + NROWS / 128; i += 256)
        atomicAdd(&h[tgt[i]], 1);
    __syncthreads();
    for (int i = t; i < NCLS; i += 256)
        if (h[i]) atomicAdd(&counts[i], h[i]);
}

// Prefix sum over 512 counts (exclusive) + n_absent. One block of 512.
__global__ __launch_bounds__(512) void k_prefix(
    const int* __restrict__ counts, int* __restrict__ offs,
    int* __restrict__ cursor, float* __restrict__ nabsG) {
    __shared__ int sc[NCLS];
    __shared__ int za;
    int t = threadIdx.x;
    int c = counts[t];
    sc[t] = c;
    if (t == 0) za = 0;
    __syncthreads();
    for (int off = 1; off < NCLS; off <<= 1) {
        int v = (t >= off) ? sc[t - off] : 0;
        __syncthreads();
        sc[t] += v;
        __syncthreads();
    }
    int excl = sc[t] - c;
    offs[t] = excl;
    cursor[t] = excl;
    if (c == 0) atomicAdd(&za, 1);
    __syncthreads();
    if (t == 0) *nabsG = (float)za;
}

// Scatter row indices bucketed by class.
__global__ __launch_bounds__(256) void k_scatter(
    const int* __restrict__ tgt, int* __restrict__ cursor, int* __restrict__ ridx) {
    int i = blockIdx.x * 256 + threadIdx.x;
    int c = tgt[i];
    int pos = atomicAdd(&cursor[c], 1);
    ridx[pos] = i;
}

// Per-class mean + L2-normalize -> bf16 centers. 1 class/block, 8 waves/class.
__global__ __launch_bounds__(512) void k_centers(
    const unsigned short* __restrict__ xb, const int* __restrict__ ridx,
    const int* __restrict__ counts, const int* __restrict__ offs,
    unsigned short* __restrict__ cen) {
    __shared__ float2 sP[8][64];
    int t = threadIdx.x, w = t >> 6, l = t & 63;
    int cl = blockIdx.x;
    int cnt = counts[cl], start = offs[cl];
    const uint32_t* xb32 = (const uint32_t*)xb;
    float a0 = 0.0f, a1 = 0.0f;
    int per = (cnt + 7) >> 3;
    int lo = w * per, hi = min(cnt, lo + per);
    int i = lo;
    for (; i + 8 <= hi; i += 8) {
        int id[8]; uint32_t v[8];
#pragma unroll
        for (int j = 0; j < 8; ++j) id[j] = ridx[start + i + j];
#pragma unroll
        for (int j = 0; j < 8; ++j) v[j] = xb32[(size_t)id[j] * 64 + l];
#pragma unroll
        for (int j = 0; j < 8; ++j) { a0 += bflo(v[j]); a1 += bfhi(v[j]); }
    }
    for (; i < hi; ++i) {
        uint32_t v = xb32[(size_t)ridx[start + i] * 64 + l];
        a0 += bflo(v); a1 += bfhi(v);
    }
    sP[w][l] = make_float2(a0, a1);
    __syncthreads();
    if (w == 0) {
        float c0 = 0.0f, c1 = 0.0f;
#pragma unroll
        for (int q = 0; q < 8; ++q) { c0 += sP[q][l].x; c1 += sP[q][l].y; }
        float fc = fmaxf((float)cnt, 1.0f);
        c0 /= fc; c1 /= fc;
        float ss = c0 * c0 + c1 * c1;
        for (int off = 1; off < 64; off <<= 1) ss += __shfl_xor(ss, off);
        float inv = 1.0f / fmaxf(sqrtf(ss), 1e-12f);
        ushort2 o;
        o.x = f2bf(c0 * inv); o.y = f2bf(c1 * inv);
        *reinterpret_cast<ushort2*>(cen + (size_t)cl * DDIM + l * 2) = o;
    }
}

// K4: 256 blocks x 8 waves. Wave w holds centers[w*64..w*64+64) as A-frags
// in registers (loaded once). 16 x-tiles of 64 samples, double-buffered 16KB
// LDS (XOR-swizzled). Absent classes contribute exp(0)=1 -> subtract nabs.
__global__ __launch_bounds__(512) void k4_loss(
    const unsigned short* __restrict__ xb, const unsigned short* __restrict__ cen,
    const int* __restrict__ tgt, const float* __restrict__ nabsG,
    float* __restrict__ out) {
    __shared__ char xL[2][16384];
    __shared__ float denP[8][64];
    __shared__ float posP[8][64];
    int t = threadIdx.x, w = t >> 6, l = t & 63;
    int lm = l & 15, lk = l >> 4;
    float nabs = *nabsG;

    v8bf afr[4][4];
#pragma unroll
    for (int m = 0; m < 4; ++m)
#pragma unroll
        for (int kc = 0; kc < 4; ++kc) {
            int row = w * 64 + m * 16 + lm;
            afr[m][kc] = *reinterpret_cast<const v8bf*>(cen + (size_t)row * DDIM + kc * 32 + lk * 8);
        }

    int block0 = blockIdx.x * 1024;
    int c0 = t * 2;
    int srow = c0 >> 4;
    int sw = (srow & 7) << 4;
    int dst0 = srow * 256 + (((c0 & 15) * 16) ^ sw);
    int dst1 = srow * 256 + ((((c0 & 15) + 1) * 16) ^ sw);
    const char* xbB = (const char*)xb;

    uint4 r0 = *(const uint4*)(xbB + (size_t)block0 * 256 + c0 * 16);
    uint4 r1 = *(const uint4*)(xbB + (size_t)block0 * 256 + c0 * 16 + 16);
    *(uint4*)(xL[0] + dst0) = r0;
    *(uint4*)(xL[0] + dst1) = r1;
    float lossAcc = 0.0f;
    __syncthreads();

    for (int tile = 0; tile < 16; ++tile) {
        int cur = tile & 1;
        int gbase = block0 + tile * 64;
        if (tile < 15) {
            const char* src = xbB + (size_t)(gbase + 64) * 256;
            r0 = *(const uint4*)(src + c0 * 16);
            r1 = *(const uint4*)(src + c0 * 16 + 16);
        }
        int ts[4];
#pragma unroll
        for (int n = 0; n < 4; ++n) ts[n] = tgt[gbase + n * 16 + lm];

        v4f acc[4][4];
        v4f zero = {0.0f, 0.0f, 0.0f, 0.0f};
#pragma unroll
        for (int m = 0; m < 4; ++m)
#pragma unroll
            for (int n = 0; n < 4; ++n) acc[m][n] = zero;

#pragma unroll
        for (int kc = 0; kc < 4; ++kc) {
            int kb = kc * 64 + lk * 16;
            v8bf b[4];
#pragma unroll
            for (int n = 0; n < 4; ++n) {
                int row = n * 16 + lm;
                b[n] = *reinterpret_cast<const v8bf*>(xL[cur] + row * 256 + (kb ^ ((row & 7) << 4)));
            }
#pragma unroll
            for (int m = 0; m < 4; ++m)
#pragma unroll
                for (int n = 0; n < 4; ++n)
                    acc[m][n] = __builtin_amdgcn_mfma_f32_16x16x32_bf16(afr[m][kc], b[n], acc[m][n], 0, 0, 0);
        }

#pragma unroll
        for (int n = 0; n < 4; ++n) {
            float se = 0.0f, sp = 0.0f;
#pragma unroll
            for (int m = 0; m < 4; ++m) {
#pragma unroll
                for (int r = 0; r < 4; ++r) {
                    int cls = w * 64 + m * 16 + lk * 4 + r;
                    float logit = acc[m][n][r] * INV_BETA;
                    se += __expf(logit);
                    if (cls == ts[n]) sp = logit;
                }
            }
            se += __shfl_xor(se, 16); se += __shfl_xor(se, 32);
            sp += __shfl_xor(sp, 16); sp += __shfl_xor(sp, 32);
            if (l < 16) { denP[w][n * 16 + lm] = se; posP[w][n * 16 + lm] = sp; }
        }
        __syncthreads();
        if (tile < 15) {
            *(uint4*)(xL[1 - cur] + dst0) = r0;
            *(uint4*)(xL[1 - cur] + dst1) = r1;
        }
        if (w == 0) {
            float den = 0.0f, pos = 0.0f;
#pragma unroll
            for (int q = 0; q < 8; ++q) { den += denP[q][l]; pos += posP[q][l]; }
            lossAcc += __logf(den - nabs) - pos;
        }
        __syncthreads();
    }
    if (w == 0) {
        for (int off = 1; off < 64; off <<= 1) lossAcc += __shfl_xor(lossAcc, off);
        if (l == 0) atomicAdd(out, lossAcc * (1.0f / NROWS));
    }
}

extern "C" void kernel_launch(void* const* d_in, const int* in_sizes, int n_in,
                              void* d_out, int out_size, void* d_ws, size_t ws_size,
                              hipStream_t stream) {
    const float* in = (const float*)d_in[0];
    const int* tgt = (const int*)d_in[1];
    float* out = (float*)d_out;
    char* ws = (char*)d_ws;
    unsigned short* xb = (unsigned short*)(ws);              // 67108864 B
    int* counts = (int*)(ws + 67108864);                     // 2048 B
    int* offs = (int*)(ws + 67110912);                       // 2048 B
    int* cursor = (int*)(ws + 67112960);                     // 2048 B
    float* nabsG = (float*)(ws + 67115008);                  // 256 B (pad)
    unsigned short* cen = (unsigned short*)(ws + 67115264);  // 131072 B
    int* ridx = (int*)(ws + 67246336);                       // 1048576 B

    hipMemsetAsync(counts, 0, 2048, stream);
    hipMemsetAsync(out, 0, sizeof(float), stream);
    hipLaunchKernelGGL(k1_normalize, dim3(2048), dim3(256), 0, stream, in, xb);
    hipLaunchKernelGGL(k_hist, dim3(128), dim3(256), 0, stream, tgt, counts);
    hipLaunchKernelGGL(k_prefix, dim3(1), dim3(512), 0, stream, counts, offs, cursor, nabsG);
    hipLaunchKernelGGL(k_scatter, dim3(NROWS / 256), dim3(256), 0, stream, tgt, cursor, ridx);
    hipLaunchKernelGGL(k_centers, dim3(NCLS), dim3(512), 0, stream, xb, ridx, counts, offs, cen);
    hipLaunchKernelGGL(k4_loss, dim3(256), dim3(512), 0, stream, xb, cen, tgt, nabsG, out);
}

// Round 7
// 133.607 us; speedup vs baseline: 3.4293x; 1.5395x over previous
//
#include <hip/hip_runtime.h>
#include <stdint.h>

#define NROWS 262144
#define DDIM 128
#define NCLS 512
#define NHB 128  // hist/scatter blocks
constexpr float INV_BETA = 10.0f;

typedef __bf16 v8bf __attribute__((ext_vector_type(8)));
typedef float v4f __attribute__((ext_vector_type(4)));

__device__ inline unsigned short f2bf(float f) {
    uint32_t u = __builtin_bit_cast(uint32_t, f);
    u += 0x7FFFu + ((u >> 16) & 1u);
    return (unsigned short)(u >> 16);
}
__device__ inline float bflo(uint32_t u) { return __builtin_bit_cast(float, u << 16); }
__device__ inline float bfhi(uint32_t u) { return __builtin_bit_cast(float, u & 0xFFFF0000u); }

// K1 v2: pure streaming L2-normalize fp32 -> bf16. No atomics, no divergence.
__global__ __launch_bounds__(256) void k1_normalize(
    const float* __restrict__ in, unsigned short* __restrict__ xb) {
    int t = threadIdx.x;
    int w = t >> 6;
    int half = (t & 63) >> 5;
    int lane32 = t & 31;
    const int CH = NROWS / 2;  // 131072
    for (int row = blockIdx.x * 8 + w * 2 + half; row < CH; row += 2048 * 8) {
        int rowB = row + CH;
        const float4 v0 = *reinterpret_cast<const float4*>(in + (size_t)row * DDIM + lane32 * 4);
        const float4 v1 = *reinterpret_cast<const float4*>(in + (size_t)rowB * DDIM + lane32 * 4);
        float s0 = v0.x * v0.x + v0.y * v0.y + v0.z * v0.z + v0.w * v0.w;
        float s1 = v1.x * v1.x + v1.y * v1.y + v1.z * v1.z + v1.w * v1.w;
#pragma unroll
        for (int off = 1; off < 32; off <<= 1) {
            s0 += __shfl_xor(s0, off);
            s1 += __shfl_xor(s1, off);
        }
        float i0 = rsqrtf(fmaxf(s0, 1e-24f));
        float i1 = rsqrtf(fmaxf(s1, 1e-24f));
        ushort4 o0, o1;
        o0.x = f2bf(v0.x * i0); o0.y = f2bf(v0.y * i0);
        o0.z = f2bf(v0.z * i0); o0.w = f2bf(v0.w * i0);
        o1.x = f2bf(v1.x * i1); o1.y = f2bf(v1.y * i1);
        o1.z = f2bf(v1.z * i1); o1.w = f2bf(v1.w * i1);
        *reinterpret_cast<ushort4*>(xb + (size_t)row * DDIM + lane32 * 4) = o0;
        *reinterpret_cast<ushort4*>(xb + (size_t)rowB * DDIM + lane32 * 4) = o1;
    }
}

// Class histogram: LDS-privatized; writes per-block hist bh[b][c] + merged counts.
__global__ __launch_bounds__(256) void k_hist(
    const int* __restrict__ tgt, int* __restrict__ counts, int* __restrict__ bh) {
    __shared__ int h[NCLS];
    int t = threadIdx.x;
    for (int i = t; i < NCLS; i += 256) h[i] = 0;
    __syncthreads();
    int base = blockIdx.x * (NROWS / NHB);
    for (int i = base + t; i < base + NROWS / NHB; i += 256)
        atomicAdd(&h[tgt[i]], 1);
    __syncthreads();
    for (int i = t; i < NCLS; i += 256) {
        int v = h[i];
        bh[blockIdx.x * NCLS + i] = v;
        if (v) atomicAdd(&counts[i], v);
    }
}

// Prefix: class offsets (exclusive scan), n_absent, and per-block bases
// base[b][c] = offs[c] + sum_{b'<b} bh[b'][c]. One block of 512.
__global__ __launch_bounds__(512) void k_prefix(
    const int* __restrict__ counts, const int* __restrict__ bh,
    int* __restrict__ offs, int* __restrict__ base, float* __restrict__ nabsG) {
    __shared__ int sc[NCLS];
    __shared__ int za;
    int t = threadIdx.x;
    int c = counts[t];
    sc[t] = c;
    if (t == 0) za = 0;
    __syncthreads();
    for (int off = 1; off < NCLS; off <<= 1) {
        int v = (t >= off) ? sc[t - off] : 0;
        __syncthreads();
        sc[t] += v;
        __syncthreads();
    }
    int excl = sc[t] - c;
    offs[t] = excl;
    if (c == 0) atomicAdd(&za, 1);
    int run = excl;
    for (int b = 0; b < NHB; ++b) {
        base[b * NCLS + t] = run;
        run += bh[b * NCLS + t];
    }
    __syncthreads();
    if (t == 0) *nabsG = (float)za;
}

// Scatter v2: per-block LDS cursors seeded from deterministic bases. No global atomics.
__global__ __launch_bounds__(256) void k_scatter(
    const int* __restrict__ tgt, const int* __restrict__ base, int* __restrict__ ridx) {
    __shared__ int cur[NCLS];
    int t = threadIdx.x;
    int b = blockIdx.x;
    cur[t] = base[b * NCLS + t];
    cur[t + 256] = base[b * NCLS + t + 256];
    __syncthreads();
    int r0 = b * (NROWS / NHB);
    for (int i = t; i < NROWS / NHB; i += 256) {
        int row = r0 + i;
        int c = tgt[row];
        int pos = atomicAdd(&cur[c], 1);
        ridx[pos] = row;
    }
}

// Per-class mean + L2-normalize -> bf16 centers. 1 class/block, 8 waves/class.
__global__ __launch_bounds__(512) void k_centers(
    const unsigned short* __restrict__ xb, const int* __restrict__ ridx,
    const int* __restrict__ counts, const int* __restrict__ offs,
    unsigned short* __restrict__ cen) {
    __shared__ float2 sP[8][64];
    int t = threadIdx.x, w = t >> 6, l = t & 63;
    int cl = blockIdx.x;
    int cnt = counts[cl], start = offs[cl];
    const uint32_t* xb32 = (const uint32_t*)xb;
    float a0 = 0.0f, a1 = 0.0f;
    int per = (cnt + 7) >> 3;
    int lo = w * per, hi = min(cnt, lo + per);
    int i = lo;
    for (; i + 8 <= hi; i += 8) {
        int id[8]; uint32_t v[8];
#pragma unroll
        for (int j = 0; j < 8; ++j) id[j] = ridx[start + i + j];
#pragma unroll
        for (int j = 0; j < 8; ++j) v[j] = xb32[(size_t)id[j] * 64 + l];
#pragma unroll
        for (int j = 0; j < 8; ++j) { a0 += bflo(v[j]); a1 += bfhi(v[j]); }
    }
    for (; i < hi; ++i) {
        uint32_t v = xb32[(size_t)ridx[start + i] * 64 + l];
        a0 += bflo(v); a1 += bfhi(v);
    }
    sP[w][l] = make_float2(a0, a1);
    __syncthreads();
    if (w == 0) {
        float c0 = 0.0f, c1 = 0.0f;
#pragma unroll
        for (int q = 0; q < 8; ++q) { c0 += sP[q][l].x; c1 += sP[q][l].y; }
        float fc = fmaxf((float)cnt, 1.0f);
        c0 /= fc; c1 /= fc;
        float ss = c0 * c0 + c1 * c1;
        for (int off = 1; off < 64; off <<= 1) ss += __shfl_xor(ss, off);
        float inv = 1.0f / fmaxf(sqrtf(ss), 1e-12f);
        ushort2 o;
        o.x = f2bf(c0 * inv); o.y = f2bf(c1 * inv);
        *reinterpret_cast<ushort2*>(cen + (size_t)cl * DDIM + l * 2) = o;
    }
}

// K4: 256 blocks x 8 waves. Wave w holds centers[w*64..w*64+64) as A-frags
// in registers. 16 x-tiles of 64 samples, double-buffered 16KB LDS (swizzled).
__global__ __launch_bounds__(512) void k4_loss(
    const unsigned short* __restrict__ xb, const unsigned short* __restrict__ cen,
    const int* __restrict__ tgt, const float* __restrict__ nabsG,
    float* __restrict__ out) {
    __shared__ char xL[2][16384];
    __shared__ float denP[8][64];
    __shared__ float posP[8][64];
    int t = threadIdx.x, w = t >> 6, l = t & 63;
    int lm = l & 15, lk = l >> 4;
    float nabs = *nabsG;

    v8bf afr[4][4];
#pragma unroll
    for (int m = 0; m < 4; ++m)
#pragma unroll
        for (int kc = 0; kc < 4; ++kc) {
            int row = w * 64 + m * 16 + lm;
            afr[m][kc] = *reinterpret_cast<const v8bf*>(cen + (size_t)row * DDIM + kc * 32 + lk * 8);
        }

    int block0 = blockIdx.x * 1024;
    int c0 = t * 2;
    int srow = c0 >> 4;
    int sw = (srow & 7) << 4;
    int dst0 = srow * 256 + (((c0 & 15) * 16) ^ sw);
    int dst1 = srow * 256 + ((((c0 & 15) + 1) * 16) ^ sw);
    const char* xbB = (const char*)xb;

    uint4 r0 = *(const uint4*)(xbB + (size_t)block0 * 256 + c0 * 16);
    uint4 r1 = *(const uint4*)(xbB + (size_t)block0 * 256 + c0 * 16 + 16);
    *(uint4*)(xL[0] + dst0) = r0;
    *(uint4*)(xL[0] + dst1) = r1;
    float lossAcc = 0.0f;
    __syncthreads();

    for (int tile = 0; tile < 16; ++tile) {
        int cur = tile & 1;
        int gbase = block0 + tile * 64;
        if (tile < 15) {
            const char* src = xbB + (size_t)(gbase + 64) * 256;
            r0 = *(const uint4*)(src + c0 * 16);
            r1 = *(const uint4*)(src + c0 * 16 + 16);
        }
        int ts[4];
#pragma unroll
        for (int n = 0; n < 4; ++n) ts[n] = tgt[gbase + n * 16 + lm];

        v4f acc[4][4];
        v4f zero = {0.0f, 0.0f, 0.0f, 0.0f};
#pragma unroll
        for (int m = 0; m < 4; ++m)
#pragma unroll
            for (int n = 0; n < 4; ++n) acc[m][n] = zero;

#pragma unroll
        for (int kc = 0; kc < 4; ++kc) {
            int kb = kc * 64 + lk * 16;
            v8bf b[4];
#pragma unroll
            for (int n = 0; n < 4; ++n) {
                int row = n * 16 + lm;
                b[n] = *reinterpret_cast<const v8bf*>(xL[cur] + row * 256 + (kb ^ ((row & 7) << 4)));
            }
#pragma unroll
            for (int m = 0; m < 4; ++m)
#pragma unroll
                for (int n = 0; n < 4; ++n)
                    acc[m][n] = __builtin_amdgcn_mfma_f32_16x16x32_bf16(afr[m][kc], b[n], acc[m][n], 0, 0, 0);
        }

#pragma unroll
        for (int n = 0; n < 4; ++n) {
            float se = 0.0f, sp = 0.0f;
#pragma unroll
            for (int m = 0; m < 4; ++m) {
#pragma unroll
                for (int r = 0; r < 4; ++r) {
                    int cls = w * 64 + m * 16 + lk * 4 + r;
                    float logit = acc[m][n][r] * INV_BETA;
                    se += __expf(logit);
                    if (cls == ts[n]) sp = logit;
                }
            }
            se += __shfl_xor(se, 16); se += __shfl_xor(se, 32);
            sp += __shfl_xor(sp, 16); sp += __shfl_xor(sp, 32);
            if (l < 16) { denP[w][n * 16 + lm] = se; posP[w][n * 16 + lm] = sp; }
        }
        __syncthreads();
        if (tile < 15) {
            *(uint4*)(xL[1 - cur] + dst0) = r0;
            *(uint4*)(xL[1 - cur] + dst1) = r1;
        }
        if (w == 0) {
            float den = 0.0f, pos = 0.0f;
#pragma unroll
            for (int q = 0; q < 8; ++q) { den += denP[q][l]; pos += posP[q][l]; }
            lossAcc += __logf(den - nabs) - pos;
        }
        __syncthreads();
    }
    if (w == 0) {
        for (int off = 1; off < 64; off <<= 1) lossAcc += __shfl_xor(lossAcc, off);
        if (l == 0) atomicAdd(out, lossAcc * (1.0f / NROWS));
    }
}

extern "C" void kernel_launch(void* const* d_in, const int* in_sizes, int n_in,
                              void* d_out, int out_size, void* d_ws, size_t ws_size,
                              hipStream_t stream) {
    const float* in = (const float*)d_in[0];
    const int* tgt = (const int*)d_in[1];
    float* out = (float*)d_out;
    char* ws = (char*)d_ws;
    unsigned short* xb = (unsigned short*)(ws);              // 67108864 B
    int* counts = (int*)(ws + 67108864);                     // 2048 B
    int* offs = (int*)(ws + 67110912);                       // 2048 B
    float* nabsG = (float*)(ws + 67112960);                  // 256 B (pad)
    unsigned short* cen = (unsigned short*)(ws + 67115264);  // 131072 B
    int* ridx = (int*)(ws + 67246336);                       // 1048576 B
    int* bh = (int*)(ws + 68294912);                         // 262144 B
    int* base = (int*)(ws + 68557056);                       // 262144 B

    hipMemsetAsync(counts, 0, 2048, stream);
    hipMemsetAsync(out, 0, sizeof(float), stream);
    hipLaunchKernelGGL(k1_normalize, dim3(2048), dim3(256), 0, stream, in, xb);
    hipLaunchKernelGGL(k_hist, dim3(NHB), dim3(256), 0, stream, tgt, counts, bh);
    hipLaunchKernelGGL(k_prefix, dim3(1), dim3(512), 0, stream, counts, bh, offs, base, nabsG);
    hipLaunchKernelGGL(k_scatter, dim3(NHB), dim3(256), 0, stream, tgt, base, ridx);
    hipLaunchKernelGGL(k_centers, dim3(NCLS), dim3(512), 0, stream, xb, ridx, counts, offs, cen);
    hipLaunchKernelGGL(k4_loss, dim3(256), dim3(512), 0, stream, xb, cen, tgt, nabsG, out);
}